// Round 3
// baseline (78.871 us; speedup 1.0000x reference)
//
#include <hip/hip_runtime.h>

// Problem constants (from reference)
constexpr int B  = 2048;   // batch
constexpr int T  = 128;    // trees
constexpr int F  = 256;    // features
constexpr int N  = 127;    // nodes per tree in input tensors
constexpr int NU = 63;     // nodes actually used (traversal layers 0..5)
constexpr int L  = 64;     // leaves per tree

// ---------------------------------------------------------------------------
// Kernel A: recover {split_idx, bias} per used node from the one-hot weights.
// Full float4 stream over weights (T*N*F floats = 16.6 MB, 16 B/lane).
// Exactly one 1.0 per 256-float node row; the hit lane packs {feature,bias}
// into an int2 record, stored TRANSPOSED: nodes[heap_idx * T + tree], so
// kernel B's per-level reads are coalesced across its 128 threads.
// Every used-node record is written each launch (one-hot guarantees a hit),
// so the 0xAA-poisoned d_ws needs no pre-clearing.
// ---------------------------------------------------------------------------
__global__ __launch_bounds__(256) void extract_kernel(const float4* __restrict__ w4,
                                                      const float* __restrict__ biases,
                                                      int2* __restrict__ nodes) {
    const int i = blockIdx.x * 256 + threadIdx.x;   // float4 index
    const float4 v = w4[i];
#pragma unroll
    for (int j = 0; j < 4; ++j) {
        const float val = (j == 0) ? v.x : (j == 1) ? v.y : (j == 2) ? v.z : v.w;
        if (val > 0.5f) {
            const int e = i * 4 + j;        // flat float index into (T,N,F)
            const int f = e & (F - 1);      // feature = e % 256
            const int g = e >> 8;           // global node = t*N + n
            const int t = g / N;            // compiler magic-mul div by 127
            const int n = g - t * N;
            if (n < NU) {
                int2 rec;
                rec.x = f;
                rec.y = __float_as_int(biases[g]);
                nodes[n * T + t] = rec;     // transposed store
            }
        }
    }
}

// ---------------------------------------------------------------------------
// Kernel B: forest traversal + reduction. One 128-thread block per batch row;
// thread t walks tree t: 6 dependent levels of {packed node load (L2) +
// x-gather (LDS) + compare}; then block-reduce 128 leaf values + base_score.
// Node table (63 KB) + leaves (32 KB) are L2-resident after first touches.
// Transposed node layout: at level l, lane t reads nodes[idx*T + t] where
// idx spans at most 2^l values -> early levels fully coalesced.
// ---------------------------------------------------------------------------
__global__ __launch_bounds__(128) void traverse_kernel(const float* __restrict__ x,
                                                       const float* __restrict__ leaves,
                                                       const float* __restrict__ base,
                                                       const int2* __restrict__ nodes,
                                                       float* __restrict__ out) {
    const int b = blockIdx.x;    // batch row
    const int t = threadIdx.x;   // tree index

    __shared__ float xs[F];
    reinterpret_cast<float2*>(xs)[t] =
        reinterpret_cast<const float2*>(x + (size_t)b * F)[t];
    __syncthreads();

    int idx = 0;                 // heap index, 0..62
#pragma unroll
    for (int l = 0; l < 6; ++l) {
        const int2  nd = nodes[idx * T + t];
        const float c  = xs[nd.x] - __int_as_float(nd.y);
        idx = 2 * idx + 1 + (c > 0.0f ? 1 : 0);
    }
    float pred = leaves[t * L + (idx - NU)];

    // 128-value reduction: 64-lane butterfly per wave, then combine waves.
#pragma unroll
    for (int off = 32; off > 0; off >>= 1)
        pred += __shfl_down(pred, off, 64);

    __shared__ float wsum[2];
    if ((t & 63) == 0) wsum[t >> 6] = pred;
    __syncthreads();
    if (t == 0) out[b] = wsum[0] + wsum[1] + base[0];
}

// ---------------------------------------------------------------------------
extern "C" void kernel_launch(void* const* d_in, const int* in_sizes, int n_in,
                              void* d_out, int out_size, void* d_ws, size_t ws_size,
                              hipStream_t stream) {
    const float* x       = (const float*)d_in[0];   // (B, F)
    const float* weights = (const float*)d_in[1];   // (T, N, F) one-hot
    const float* biases  = (const float*)d_in[2];   // (T, N)
    const float* leaves  = (const float*)d_in[3];   // (T, L)
    const float* base    = (const float*)d_in[4];   // (1,)
    float* out = (float*)d_out;                     // (B,)

    int2* nodes = (int2*)d_ws;                      // NU*T int2 = 63 KB scratch

    // T*N*F/4 float4s / 256 threads = 4064 blocks exactly.
    extract_kernel<<<(T * N * F / 4) / 256, 256, 0, stream>>>(
        (const float4*)weights, biases, nodes);
    traverse_kernel<<<B, 128, 0, stream>>>(x, leaves, base, nodes, out);
}

// Round 4
// 78.740 us; speedup vs baseline: 1.0017x; 1.0017x over previous
//
#include <hip/hip_runtime.h>

// Problem constants (from reference)
constexpr int B  = 2048;   // batch
constexpr int T  = 128;    // trees
constexpr int F  = 256;    // features
constexpr int N  = 127;    // nodes per tree in input tensors
constexpr int NU = 63;     // nodes actually used (traversal layers 0..5)
constexpr int L  = 64;     // leaves per tree

// ---------------------------------------------------------------------------
// Kernel A: recover {split_idx, bias} per used node from the one-hot weights.
// Only the first NU=63 rows of each tree's 127-row block are used, so we scan
// just those: used-row id r = t*63+n maps to source row t*127+n. Reads are
// float4 (16 B/lane), 63 KB contiguous runs per tree -> ~8.3 MB total stream.
// The single hit lane per row packs {feature, bias} into an int2, stored
// TRANSPOSED (nodes[n*T + t]) so kernel B's per-level reads coalesce.
// One-hot guarantees every record is written -> no d_ws pre-clear needed.
// ---------------------------------------------------------------------------
__global__ __launch_bounds__(256) void extract_kernel(const float4* __restrict__ w4,
                                                      const float* __restrict__ biases,
                                                      int2* __restrict__ nodes) {
    const int i = blockIdx.x * 256 + threadIdx.x;   // 0 .. T*NU*64-1
    const int r = i >> 6;                            // used-row id = t*NU+n
    const int c = i & 63;                            // float4 index within row
    const int t = r / NU;                            // magic-mul div by 63
    const int n = r - t * NU;
    const float4 v = w4[((size_t)t * N + n) * (F / 4) + c];
#pragma unroll
    for (int j = 0; j < 4; ++j) {
        const float val = (j == 0) ? v.x : (j == 1) ? v.y : (j == 2) ? v.z : v.w;
        if (val > 0.5f) {
            int2 rec;
            rec.x = c * 4 + j;                       // feature index
            rec.y = __float_as_int(biases[t * N + n]);
            nodes[n * T + t] = rec;                  // transposed store
        }
    }
}

// ---------------------------------------------------------------------------
// Kernel B: forest traversal + reduction. One 128-thread block per batch row;
// thread t walks tree t. Both children of the current node are prefetched
// while the current level's LDS gather + compare resolve, cutting the
// dependent chain from (L2+LDS) to max(L2, LDS) per level. Node table
// (63 KB) + leaves (32 KB) are L2-resident. Then 128-value block reduction
// + base_score.
// ---------------------------------------------------------------------------
__global__ __launch_bounds__(128) void traverse_kernel(const float* __restrict__ x,
                                                       const float* __restrict__ leaves,
                                                       const float* __restrict__ base,
                                                       const int2* __restrict__ nodes,
                                                       float* __restrict__ out) {
    const int b = blockIdx.x;    // batch row
    const int t = threadIdx.x;   // tree index

    __shared__ float xs[F];
    reinterpret_cast<float2*>(xs)[t] =
        reinterpret_cast<const float2*>(x + (size_t)b * F)[t];
    __syncthreads();

    int idx = 0;
    int2 nd = nodes[t];          // root record, fully coalesced
#pragma unroll
    for (int l = 0; l < 5; ++l) {
        // Prefetch both children before this level's compare resolves.
        const int2 cl = nodes[(2 * idx + 1) * T + t];
        const int2 cr = nodes[(2 * idx + 2) * T + t];
        const bool right = xs[nd.x] > __int_as_float(nd.y);
        idx = 2 * idx + 1 + (right ? 1 : 0);
        nd = right ? cr : cl;
    }
    const bool right = xs[nd.x] > __int_as_float(nd.y);
    idx = 2 * idx + 1 + (right ? 1 : 0);
    float pred = leaves[t * L + (idx - NU)];

    // 128-value reduction: 64-lane butterfly per wave, then combine waves.
#pragma unroll
    for (int off = 32; off > 0; off >>= 1)
        pred += __shfl_down(pred, off, 64);

    __shared__ float wsum[2];
    if ((t & 63) == 0) wsum[t >> 6] = pred;
    __syncthreads();
    if (t == 0) out[b] = wsum[0] + wsum[1] + base[0];
}

// ---------------------------------------------------------------------------
extern "C" void kernel_launch(void* const* d_in, const int* in_sizes, int n_in,
                              void* d_out, int out_size, void* d_ws, size_t ws_size,
                              hipStream_t stream) {
    const float* x       = (const float*)d_in[0];   // (B, F)
    const float* weights = (const float*)d_in[1];   // (T, N, F) one-hot
    const float* biases  = (const float*)d_in[2];   // (T, N)
    const float* leaves  = (const float*)d_in[3];   // (T, L)
    const float* base    = (const float*)d_in[4];   // (1,)
    float* out = (float*)d_out;                     // (B,)

    int2* nodes = (int2*)d_ws;                      // NU*T int2 = 63 KB scratch

    // T*NU rows x 64 float4 = 516096 float4s / 256 threads = 2016 blocks.
    extract_kernel<<<(T * NU * (F / 4)) / 256, 256, 0, stream>>>(
        (const float4*)weights, biases, nodes);
    traverse_kernel<<<B, 128, 0, stream>>>(x, leaves, base, nodes, out);
}